// Round 1
// 284.284 us; speedup vs baseline: 1.0926x; 1.0926x over previous
//
#include <hip/hip_runtime.h>
#include <hip/hip_bf16.h>

// EdgeConv, CSR-by-dst with XCD-sharded build, bf16 intermediates:
//   abf[n] = bf16(h@W1[0:64]); bsf[n] = bf16(h@W1[64:128]+b1)
//   acc[n] = sum_{e:dst=n} relu(abf[src] + bsf[n] + e*w128)   (wave/node, lane=feat)
//   out[n] = acc[n] @ W2 + cnt[n]*b2                          (fused readlane matvec)
// node_accum v2: meta staged lane-parallel into registers (1 vector load / 64 edges),
// per-edge src/e via v_readlane -> gather addr is SALU-uniform; vmcnt queue holds
// ONLY gathers so the 8-deep prefetch window actually stays filled (old version
// serialized on the per-edge meta load -> ~1 outstanding line/wave).

#define NSH 8

// ---------------- count ----------------
__global__ void count_kernel(const int* __restrict__ dst, int* __restrict__ counts, int n_edges) {
    int i = blockIdx.x * blockDim.x + threadIdx.x;
    if (i < n_edges) atomicAdd(&counts[dst[i]], 1);
}

// ---------------- per-shard totals (block = 256 nodes, single shard) ----------------
__global__ __launch_bounds__(256) void shard_sum_kernel(const int* __restrict__ counts,
                                                        int* __restrict__ shardTotal,
                                                        int n, int shsz) {
    __shared__ int ws[4];
    const int i    = blockIdx.x * 256 + threadIdx.x;
    const int lane = threadIdx.x & 63;
    const int wv   = threadIdx.x >> 6;
    int c = (i < n) ? counts[i] : 0;
    #pragma unroll
    for (int d = 1; d < 64; d <<= 1) c += __shfl_xor(c, d, 64);
    if (lane == 0) ws[wv] = c;
    __syncthreads();
    if (threadIdx.x == 0)
        atomicAdd(&shardTotal[(blockIdx.x * 256) / shsz], ws[0] + ws[1] + ws[2] + ws[3]);
}

// ---------------- shard-contiguous offset allocation ----------------
__global__ __launch_bounds__(256) void alloc_offs_kernel(const int* __restrict__ counts,
                                                         const int* __restrict__ shardTotal,
                                                         int* __restrict__ shard_cursor,
                                                         int* __restrict__ offs, int n, int shsz) {
    __shared__ int wsum[4];
    const int i     = blockIdx.x * 256 + threadIdx.x;
    const int lane  = threadIdx.x & 63;
    const int wv    = threadIdx.x >> 6;
    const int shard = (blockIdx.x * 256) / shsz;   // uniform (shsz % 256 == 0)

    const int c = (i < n) ? counts[i] : 0;
    int incl = c;
    #pragma unroll
    for (int d = 1; d < 64; d <<= 1) {
        int v = __shfl_up(incl, d, 64);
        if (lane >= d) incl += v;
    }
    const int excl = incl - c;
    if (lane == 63) wsum[wv] = incl;
    __syncthreads();
    if (threadIdx.x == 0) {
        int base0 = 0;
        #pragma unroll
        for (int t = 0; t < NSH; ++t) if (t < shard) base0 += shardTotal[t];
        const int s0 = wsum[0], s1 = wsum[1], s2 = wsum[2], s3 = wsum[3];
        const int b = base0 + atomicAdd(&shard_cursor[shard], s0 + s1 + s2 + s3);
        wsum[0] = b; wsum[1] = b + s0; wsum[2] = b + s0 + s1; wsum[3] = b + s0 + s1 + s2;
    }
    __syncthreads();
    if (i < n) offs[i] = wsum[wv] + excl;
}

// ---------------- XCD-sharded fill: shard = bid & 7 ----------------
__global__ void fill_shard_kernel(const int* __restrict__ dst, const int* __restrict__ src,
                                  const float* __restrict__ e,
                                  const int* __restrict__ offs, int* __restrict__ cursor,
                                  int2* __restrict__ meta, int n_edges, int shsz) {
    const int shard = blockIdx.x & (NSH - 1);
    const int i = (blockIdx.x >> 3) * 256 + threadIdx.x;
    if (i >= n_edges) return;
    const int d = dst[i];
    const int lo = shard * shsz;
    if (d >= lo && d < lo + shsz) {
        const int pos = offs[d] + atomicAdd(&cursor[d], 1);   // XCD-local line
        meta[pos] = make_int2(src[i], __float_as_int(e[i]));  // XCD-local scatter
    }
}

// ---------------- abf = bf16(h@W1t), bsf = bf16(h@W1b + b1) ----------------
__global__ __launch_bounds__(256) void precompute_ab_kernel(
    const float* __restrict__ h, const float* __restrict__ W1, const float* __restrict__ b1,
    unsigned short* __restrict__ abf, unsigned short* __restrict__ bsf, int n_nodes)
{
    const int lane = threadIdx.x & 63;
    const int wv   = threadIdx.x >> 6;
    const int j0   = __builtin_amdgcn_readfirstlane((wv & 1) << 5);  // wave-uniform 0/32
    const int n    = blockIdx.x * 128 + ((wv >> 1) << 6) + lane;
    if (n >= n_nodes) return;

    float4 x4[16];
    const float4* hp = reinterpret_cast<const float4*>(h + (size_t)n * 64);
    #pragma unroll
    for (int k4 = 0; k4 < 16; ++k4) x4[k4] = hp[k4];

    float av[32], bv[32];
    #pragma unroll
    for (int j = 0; j < 32; ++j) { av[j] = 0.f; bv[j] = b1[j0 + j]; }

    const float* __restrict__ W1j = W1 + j0;
    #pragma unroll
    for (int k4 = 0; k4 < 16; ++k4) {
        const float xv[4] = { x4[k4].x, x4[k4].y, x4[k4].z, x4[k4].w };
        #pragma unroll
        for (int r = 0; r < 4; ++r) {
            const float* wt = W1j + (size_t)(4 * k4 + r) * 64;        // s_load
            const float* wb = W1j + (size_t)(64 + 4 * k4 + r) * 64;   // s_load
            #pragma unroll
            for (int j = 0; j < 32; ++j) {
                av[j] = fmaf(xv[r], wt[j], av[j]);
                bv[j] = fmaf(xv[r], wb[j], bv[j]);
            }
        }
    }

    {
        uint pk[16];
        #pragma unroll
        for (int q = 0; q < 16; ++q) {
            __hip_bfloat16 l0 = __float2bfloat16(av[2 * q]);
            __hip_bfloat16 l1 = __float2bfloat16(av[2 * q + 1]);
            pk[q] = ((uint)*reinterpret_cast<unsigned short*>(&l1) << 16) |
                    *reinterpret_cast<unsigned short*>(&l0);
        }
        uint4* p4 = reinterpret_cast<uint4*>(abf + (size_t)n * 64 + j0);
        #pragma unroll
        for (int q = 0; q < 4; ++q)
            p4[q] = make_uint4(pk[4 * q], pk[4 * q + 1], pk[4 * q + 2], pk[4 * q + 3]);
    }
    {
        uint pk[16];
        #pragma unroll
        for (int q = 0; q < 16; ++q) {
            __hip_bfloat16 l0 = __float2bfloat16(bv[2 * q]);
            __hip_bfloat16 l1 = __float2bfloat16(bv[2 * q + 1]);
            pk[q] = ((uint)*reinterpret_cast<unsigned short*>(&l1) << 16) |
                    *reinterpret_cast<unsigned short*>(&l0);
        }
        uint4* p4 = reinterpret_cast<uint4*>(bsf + (size_t)n * 64 + j0);
        #pragma unroll
        for (int q = 0; q < 4; ++q)
            p4[q] = make_uint4(pk[4 * q], pk[4 * q + 1], pk[4 * q + 2], pk[4 * q + 3]);
    }
}

// ---------------- accum: wave/node, lane=feat, register-meta + depth-8 prefetch ----------------
__global__ __launch_bounds__(256) void node_accum_kernel(
    const unsigned short* __restrict__ abf, const unsigned short* __restrict__ bsf,
    const float* __restrict__ W1, const float* __restrict__ W2, const float* __restrict__ b2,
    const int* __restrict__ offs, const int* __restrict__ counts,
    const int2* __restrict__ meta, float* __restrict__ out, int n_nodes)
{
    const int lane = threadIdx.x & 63;
    const int wv   = __builtin_amdgcn_readfirstlane(threadIdx.x >> 6);
    const int n    = blockIdx.x * 4 + wv;          // wave-uniform node id
    if (n >= n_nodes) return;

    const float basel = __uint_as_float((uint)bsf[(size_t)n * 64 + lane] << 16);
    const float w128l = W1[(size_t)128 * 64 + lane];
    float acc = 0.f;

    const int beg = offs[n];     // s_load (n uniform)
    const int np  = counts[n];   // s_load

    // chunks of <=64 edges: meta staged into registers by ONE lane-parallel load,
    // per-edge src/e extracted with v_readlane (no memory on the gather-addr path)
    for (int c0 = 0; c0 < np; c0 += 64) {
        const int cn = min(np - c0, 64);

        int mx = 0, my = 0;
        if (lane < cn) {
            const int2 m = meta[beg + c0 + lane];   // 512B coalesced, once per chunk
            mx = m.x; my = m.y;
        }

        // pipeline slots hold the RAW zext ushort; <<16 happens at consume time
        uint x0=0,x1=0,x2=0,x3=0,x4=0,x5=0,x6=0,x7=0;

        auto ld = [&](int j, uint& x) {
            const int s = __builtin_amdgcn_readlane(mx, j);        // uniform src id
            x = (uint)abf[(size_t)s * 64 + lane];                  // saddr gather, 128B/wave
        };
        auto step = [&](int j, uint xr) {
            const float ev = __uint_as_float((uint)__builtin_amdgcn_readlane(my, j));
            const float xv = __uint_as_float(xr << 16);
            acc += fmaxf(fmaf(ev, w128l, basel) + xv, 0.f);
        };

        if (cn > 0) ld(0, x0);
        if (cn > 1) ld(1, x1);
        if (cn > 2) ld(2, x2);
        if (cn > 3) ld(3, x3);
        if (cn > 4) ld(4, x4);
        if (cn > 5) ld(5, x5);
        if (cn > 6) ld(6, x6);
        if (cn > 7) ld(7, x7);

        int i = 0;
        while (i + 16 <= cn) {
            step(i + 0, x0); ld(i + 8,  x0);
            step(i + 1, x1); ld(i + 9,  x1);
            step(i + 2, x2); ld(i + 10, x2);
            step(i + 3, x3); ld(i + 11, x3);
            step(i + 4, x4); ld(i + 12, x4);
            step(i + 5, x5); ld(i + 13, x5);
            step(i + 6, x6); ld(i + 14, x6);
            step(i + 7, x7); ld(i + 15, x7);
            i += 8;
        }
        const int r = cn - i;   // 0..15
        if (r > 0)  { step(i + 0, x0); }  if (r > 8)  { ld(i + 8,  x0); }
        if (r > 1)  { step(i + 1, x1); }  if (r > 9)  { ld(i + 9,  x1); }
        if (r > 2)  { step(i + 2, x2); }  if (r > 10) { ld(i + 10, x2); }
        if (r > 3)  { step(i + 3, x3); }  if (r > 11) { ld(i + 11, x3); }
        if (r > 4)  { step(i + 4, x4); }  if (r > 12) { ld(i + 12, x4); }
        if (r > 5)  { step(i + 5, x5); }  if (r > 13) { ld(i + 13, x5); }
        if (r > 6)  { step(i + 6, x6); }  if (r > 14) { ld(i + 14, x6); }
        if (r > 7)  { step(i + 7, x7); }
        if (r > 8)  { step(i + 8,  x0); }
        if (r > 9)  { step(i + 9,  x1); }
        if (r > 10) { step(i + 10, x2); }
        if (r > 11) { step(i + 11, x3); }
        if (r > 12) { step(i + 12, x4); }
        if (r > 13) { step(i + 13, x5); }
        if (r > 14) { step(i + 14, x6); }
    }

    // fused epilogue: out[n][lane] = sum_j acc_j * W2[j][lane] + np*b2[lane]
    float o = (float)np * b2[lane];
    #pragma unroll
    for (int j = 0; j < 64; ++j) {
        const float aj = __shfl(acc, j, 64);               // v_readlane
        o = fmaf(aj, W2[(size_t)j * 64 + lane], o);        // coalesced, L1-hot
    }
    out[(size_t)n * 64 + lane] = o;
}

extern "C" void kernel_launch(void* const* d_in, const int* in_sizes, int n_in,
                              void* d_out, int out_size, void* d_ws, size_t ws_size,
                              hipStream_t stream) {
    const float* h  = (const float*)d_in[0];
    const float* e  = (const float*)d_in[1];
    const int* src  = (const int*)d_in[2];
    const int* dst  = (const int*)d_in[3];
    const float* W1 = (const float*)d_in[4];
    const float* b1 = (const float*)d_in[5];
    const float* W2 = (const float*)d_in[6];
    const float* b2 = (const float*)d_in[7];
    float* out = (float*)d_out;

    const int n_edges = in_sizes[2];
    const int N = in_sizes[0] / 64;

    // shard size: multiple of 256 so every 256-node block sits in one shard
    const int shsz = ((N + NSH * 256 - 1) / (NSH * 256)) * 256;   // 12544 for N=100000

    // ws: [counts N | cursor N | shardTotal 8 | shard_cursor 8 | offs N] ints,
    //     [meta 2E] ints, [abf 64N ushort], [bsf 64N ushort]
    int* counts       = (int*)d_ws;
    int* cursor       = counts + N;
    int* shardTotal   = cursor + N;
    int* shard_cursor = shardTotal + NSH;
    int* offs         = shard_cursor + NSH;
    int2* meta        = (int2*)(offs + N);
    unsigned short* abf = (unsigned short*)(meta + n_edges);
    unsigned short* bsf = abf + (size_t)64 * N;

    // zero all atomically-updated counters every call
    hipMemsetAsync(counts, 0, ((size_t)2 * N + 2 * NSH) * sizeof(int), stream);

    const int eb = (n_edges + 255) / 256;
    const int nb = (N + 255) / 256;
    const int pg = (N + 127) / 128;

    precompute_ab_kernel<<<pg, 256, 0, stream>>>(h, W1, b1, abf, bsf, N);
    count_kernel<<<eb, 256, 0, stream>>>(dst, counts, n_edges);
    shard_sum_kernel<<<nb, 256, 0, stream>>>(counts, shardTotal, N, shsz);
    alloc_offs_kernel<<<nb, 256, 0, stream>>>(counts, shardTotal, shard_cursor, offs, N, shsz);
    fill_shard_kernel<<<eb * NSH, 256, 0, stream>>>(dst, src, e, offs, cursor, meta,
                                                    n_edges, shsz);
    node_accum_kernel<<<(N + 3) / 4, 256, 0, stream>>>(abf, bsf, W1, W2, b2,
                                                       offs, counts, meta, out, N);
}